// Round 1
// baseline (350.522 us; speedup 1.0000x reference)
//
#include <hip/hip_runtime.h>

#define HW 3136
#define NPOS 12845056   // 16*256*3136

__device__ __forceinline__ unsigned fkey(float f) {
  unsigned u = __float_as_uint(f);
  return (u & 0x80000000u) ? ~u : (u | 0x80000000u);
}
__device__ __forceinline__ float funkey(unsigned u) {
  return __uint_as_float((u & 0x80000000u) ? (u & 0x7FFFFFFFu) : ~u);
}
__device__ __forceinline__ float spikef(float x) {
  return fminf(fmaxf(rintf(x), 0.0f), 4.0f);
}

// ---------------- Kernel 1: audio pre-projection + init ----------------
__global__ __launch_bounds__(256) void prep_kernel(
    const float* __restrict__ audio, const float* __restrict__ w1,
    const float* __restrict__ b1, float* __restrict__ a_pre,
    float* __restrict__ pool, unsigned* __restrict__ mm)
{
  __shared__ float au[256];
  int b = blockIdx.x, t = threadIdx.x;
  au[t] = audio[b*256 + t];
  pool[b*256 + t] = 0.0f;
  if (b == 0 && t == 0) { mm[0] = 0xFFFFFFFFu; mm[1] = 0u; }
  __syncthreads();
  int w = t >> 6, l = t & 63;
  float a0 = au[l], a1 = au[l+64], a2 = au[l+128], a3 = au[l+192];
  for (int jj = 0; jj < 32; ++jj) {
    int j = w*32 + jj;
    const float* row = w1 + j*512 + 256;
    float s = row[l]*a0 + row[l+64]*a1 + row[l+128]*a2 + row[l+192]*a3;
    #pragma unroll
    for (int off = 32; off; off >>= 1) s += __shfl_xor(s, off);
    if (l == 0) a_pre[b*128 + j] = s + b1[j];
  }
}

// ---------------- Kernel 2: fused MLP + mi + pooling ----------------
__global__ __launch_bounds__(256) void mlp_kernel(
    const float* __restrict__ fm, const float* __restrict__ w1,
    const float* __restrict__ w2, const float* __restrict__ b2,
    const float* __restrict__ w3, const float* __restrict__ b3,
    const float* __restrict__ g1, const float* __restrict__ be1,
    const float* __restrict__ g2, const float* __restrict__ be2,
    const float* __restrict__ a_pre, float* __restrict__ mi_out,
    float* __restrict__ pool, unsigned* __restrict__ mm)
{
  __shared__ float fm_t[32][32];     // 4 KB  fm tile (k-chunk x positions)
  __shared__ float wAT[32][132];     // 16.9 KB w1 k-chunk, transposed [cc][j]
  __shared__ float h1n[128][36];     // 18.4 KB layer-1 activations [j][i]
  __shared__ float wB[64][33];       // 8.4 KB w2 k-chunk [j2][k]
  __shared__ float h2n[64][36];      // 9.2 KB layer-2 activations [j2][i]
  __shared__ float red[8][32];
  __shared__ float red2[8][32];
  __shared__ float miL[32];

  const int b = blockIdx.y, tile = blockIdx.x;
  const int s0 = tile * 32;
  const int t = threadIdx.x;
  const int ig = t >> 5;        // i base = ig*4  (8 groups x 4 = 32 positions)
  const int jg = t & 31;        // GEMM1: j = jg*4 + jj

  const size_t fm_base = (size_t)b * 256 * HW;

  // ---- GEMM1: visual @ w1v.T, k-tiled by 32 channels ----
  float acc[4][4] = {};
  for (int kt = 0; kt < 8; ++kt) {
    __syncthreads();
    { // fm tile: 32 rows x 32 cols, float4 loads
      int cc = t >> 3, q = t & 7;
      const float4 v = *reinterpret_cast<const float4*>(
          fm + fm_base + (size_t)(kt*32 + cc) * HW + s0 + q*4);
      *reinterpret_cast<float4*>(&fm_t[cc][q*4]) = v;
    }
    #pragma unroll
    for (int r = 0; r < 16; ++r) { // w1 chunk transposed
      int idx = t + r*256; int j = idx >> 5, cc = idx & 31;
      wAT[cc][j] = w1[j*512 + kt*32 + cc];
    }
    __syncthreads();
    #pragma unroll 8
    for (int cc = 0; cc < 32; ++cc) {
      const float4 f  = *reinterpret_cast<const float4*>(&fm_t[cc][ig*4]);
      const float4 wv = *reinterpret_cast<const float4*>(&wAT[cc][jg*4]);
      float fv[4] = {f.x, f.y, f.z, f.w};
      float wvv[4] = {wv.x, wv.y, wv.z, wv.w};
      #pragma unroll
      for (int ii = 0; ii < 4; ++ii)
        #pragma unroll
        for (int jj = 0; jj < 4; ++jj)
          acc[ii][jj] += fv[ii] * wvv[jj];
    }
  }
  // add audio pre-projection (+b1), scatter to h1n[j][i]
  float ap[4];
  #pragma unroll
  for (int jj = 0; jj < 4; ++jj) ap[jj] = a_pre[b*128 + jg*4 + jj];
  #pragma unroll
  for (int jj = 0; jj < 4; ++jj)
    #pragma unroll
    for (int ii = 0; ii < 4; ++ii)
      h1n[jg*4+jj][ig*4+ii] = acc[ii][jj] + ap[jj];
  __syncthreads();

  // ---- LN1 (two-pass, matches reference) + spike ----
  const int i_ = t & 31, p = t >> 5;
  {
    float s = 0;
    #pragma unroll
    for (int q = 0; q < 16; ++q) s += h1n[p*16+q][i_];
    red[p][i_] = s;
  }
  __syncthreads();
  float mu = 0;
  #pragma unroll
  for (int pp = 0; pp < 8; ++pp) mu += red[pp][i_];
  mu *= (1.0f/128.0f);
  {
    float s2 = 0;
    #pragma unroll
    for (int q = 0; q < 16; ++q) { float d = h1n[p*16+q][i_] - mu; s2 += d*d; }
    red2[p][i_] = s2;
  }
  __syncthreads();
  float var = 0;
  #pragma unroll
  for (int pp = 0; pp < 8; ++pp) var += red2[pp][i_];
  var *= (1.0f/128.0f);
  float sq = sqrtf(var + 1e-5f);
  #pragma unroll
  for (int q = 0; q < 16; ++q) {
    int j = p*16 + q;
    float v = (h1n[j][i_] - mu) / sq * g1[j] + be1[j];
    h1n[j][i_] = spikef(v);
  }
  // barrier happens at top of GEMM2 k-chunk loop

  // ---- GEMM2: h1 @ w2.T ----
  float acc2[4][2] = {};
  for (int kc = 0; kc < 4; ++kc) {
    __syncthreads();
    #pragma unroll
    for (int r = 0; r < 8; ++r) {
      int idx = t + r*256; int j2 = idx >> 5, k = idx & 31;
      wB[j2][k] = w2[j2*128 + kc*32 + k];
    }
    __syncthreads();
    #pragma unroll 8
    for (int k = 0; k < 32; ++k) {
      const float4 h = *reinterpret_cast<const float4*>(&h1n[kc*32+k][ig*4]);
      float w0 = wB[jg][k], w1v = wB[jg+32][k];
      acc2[0][0] += h.x*w0;  acc2[1][0] += h.y*w0;  acc2[2][0] += h.z*w0;  acc2[3][0] += h.w*w0;
      acc2[0][1] += h.x*w1v; acc2[1][1] += h.y*w1v; acc2[2][1] += h.z*w1v; acc2[3][1] += h.w*w1v;
    }
  }
  {
    float b2v0 = b2[jg], b2v1 = b2[jg+32];
    #pragma unroll
    for (int ii = 0; ii < 4; ++ii) {
      h2n[jg][ig*4+ii]    = acc2[ii][0] + b2v0;
      h2n[jg+32][ig*4+ii] = acc2[ii][1] + b2v1;
    }
  }
  __syncthreads();

  // ---- LN2 + spike ----
  {
    float s = 0;
    #pragma unroll
    for (int q = 0; q < 8; ++q) s += h2n[p*8+q][i_];
    red[p][i_] = s;
  }
  __syncthreads();
  float mu2 = 0;
  #pragma unroll
  for (int pp = 0; pp < 8; ++pp) mu2 += red[pp][i_];
  mu2 *= (1.0f/64.0f);
  {
    float s2 = 0;
    #pragma unroll
    for (int q = 0; q < 8; ++q) { float d = h2n[p*8+q][i_] - mu2; s2 += d*d; }
    red2[p][i_] = s2;
  }
  __syncthreads();
  float var2 = 0;
  #pragma unroll
  for (int pp = 0; pp < 8; ++pp) var2 += red2[pp][i_];
  var2 *= (1.0f/64.0f);
  float sq2 = sqrtf(var2 + 1e-5f);
  #pragma unroll
  for (int q = 0; q < 8; ++q) {
    int j = p*8 + q;
    float v = (h2n[j][i_] - mu2) / sq2 * g2[j] + be2[j];
    h2n[j][i_] = spikef(v);
  }
  __syncthreads();

  // ---- GEMM3: mi = h2 . w3 + b3 ----
  {
    float s = 0;
    #pragma unroll
    for (int q = 0; q < 8; ++q) s += h2n[p*8+q][i_] * w3[p*8+q];
    red[p][i_] = s;
  }
  __syncthreads();
  if (t < 32) {
    float m = b3[0];
    #pragma unroll
    for (int pp = 0; pp < 8; ++pp) m += red[pp][t];
    miL[t] = m;
    mi_out[b*HW + s0 + t] = m;
    float mn = m, mx = m;
    #pragma unroll
    for (int off = 16; off; off >>= 1) {
      mn = fminf(mn, __shfl_xor(mn, off));
      mx = fmaxf(mx, __shfl_xor(mx, off));
    }
    if (t == 0) {
      atomicMin(&mm[0], fkey(mn));
      atomicMax(&mm[1], fkey(mx));
    }
  }
  __syncthreads();

  // ---- pooling: pool[b][c] += sum_i mi[i] * fm[b][c][s0+i] ----
  const int cg = t >> 5;
  const float miv = miL[i_];
  for (int c = cg; c < 256; c += 8) {
    float v = fm[fm_base + (size_t)c * HW + s0 + i_] * miv;
    #pragma unroll
    for (int off = 16; off; off >>= 1) v += __shfl_xor(v, off);
    if (i_ == 0) atomicAdd(&pool[b*256 + c], v);
  }
}

// ---------------- Kernel 3: projection + LN + spike -> channel scale ----------------
__global__ __launch_bounds__(256) void scale_kernel(
    const float* __restrict__ pool, const float* __restrict__ pw,
    const float* __restrict__ pb, const float* __restrict__ pg,
    const float* __restrict__ pbeta, float* __restrict__ scale,
    const unsigned* __restrict__ mm, float* __restrict__ gpar)
{
  __shared__ float pl[256];
  __shared__ float xsh[256];
  __shared__ float rs[4], rs2[4];
  int b = blockIdx.x, t = threadIdx.x;
  pl[t] = pool[b*256 + t];
  __syncthreads();
  int w = t >> 6, l = t & 63;
  float p0 = pl[l], p1 = pl[l+64], p2 = pl[l+128], p3 = pl[l+192];
  for (int jj = 0; jj < 64; ++jj) {
    int j = w*64 + jj;
    const float* row = pw + j*256;
    float s = row[l]*p0 + row[l+64]*p1 + row[l+128]*p2 + row[l+192]*p3;
    #pragma unroll
    for (int off = 32; off; off >>= 1) s += __shfl_xor(s, off);
    if (l == 0) xsh[j] = s;
  }
  __syncthreads();
  float x = xsh[t] + pb[t];
  float s = x;
  #pragma unroll
  for (int off = 32; off; off >>= 1) s += __shfl_xor(s, off);
  if (l == 0) rs[w] = s;
  __syncthreads();
  float mu = (rs[0]+rs[1]+rs[2]+rs[3]) * (1.0f/256.0f);
  float d = x - mu;
  float s2 = d*d;
  #pragma unroll
  for (int off = 32; off; off >>= 1) s2 += __shfl_xor(s2, off);
  if (l == 0) rs2[w] = s2;
  __syncthreads();
  float var = (rs2[0]+rs2[1]+rs2[2]+rs2[3]) * (1.0f/256.0f);
  float v = d / sqrtf(var + 1e-5f) * pg[t] + pbeta[t];
  scale[b*256 + t] = spikef(v);
  if (b == 0 && t == 0) {
    float mn = funkey(mm[0]), mx = funkey(mm[1]);
    gpar[0] = mn;
    gpar[1] = mx - mn + 1e-6f;
  }
}

// ---------------- Kernel 4: fusion map + normalized mi map ----------------
__global__ __launch_bounds__(256) void fuse_kernel(
    const float4* __restrict__ fm4, const float* __restrict__ scale,
    const float4* __restrict__ mi4, const float* __restrict__ gpar,
    float4* __restrict__ out4, float4* __restrict__ mi4out)
{
  int bid = blockIdx.x;
  if (bid < 12544) {
    int idx = bid*256 + (int)threadIdx.x;
    int row = idx / 784;               // (b*256+c); 784 float4 per spatial row
    float s = scale[row];
    float4 v = fm4[idx];
    out4[idx] = make_float4(v.x*s, v.y*s, v.z*s, v.w*s);
  } else {
    int idx = (bid - 12544)*256 + (int)threadIdx.x;   // 12544 float4 of mi
    float gmin = gpar[0], den = gpar[1];
    float4 v = mi4[idx];
    mi4out[idx] = make_float4((v.x-gmin)/den, (v.y-gmin)/den,
                              (v.z-gmin)/den, (v.w-gmin)/den);
  }
}

extern "C" void kernel_launch(void* const* d_in, const int* in_sizes, int n_in,
                              void* d_out, int out_size, void* d_ws, size_t ws_size,
                              hipStream_t stream)
{
  const float* fm    = (const float*)d_in[0];
  const float* audio = (const float*)d_in[1];
  const float* w1    = (const float*)d_in[2];
  const float* b1    = (const float*)d_in[3];
  const float* g1    = (const float*)d_in[4];
  const float* be1   = (const float*)d_in[5];
  const float* w2    = (const float*)d_in[6];
  const float* b2    = (const float*)d_in[7];
  const float* g2    = (const float*)d_in[8];
  const float* be2   = (const float*)d_in[9];
  const float* w3    = (const float*)d_in[10];
  const float* b3    = (const float*)d_in[11];
  const float* pw    = (const float*)d_in[12];
  const float* pb    = (const float*)d_in[13];
  const float* pg    = (const float*)d_in[14];
  const float* pbeta = (const float*)d_in[15];

  float* ws    = (float*)d_ws;
  float* a_pre = ws;              // 2048 floats
  float* pool  = ws + 2048;       // 4096
  float* scale = ws + 6144;       // 4096
  float* mi    = ws + 10240;      // 50176 (16B aligned)
  unsigned* mm = (unsigned*)(ws + 60416);  // 2 keys
  float* gpar  = ws + 60418;      // gmin, denom

  float* out    = (float*)d_out;
  float* mi4out = out + NPOS;

  prep_kernel<<<16, 256, 0, stream>>>(audio, w1, b1, a_pre, pool, mm);
  mlp_kernel<<<dim3(98, 16), 256, 0, stream>>>(fm, w1, w2, b2, w3, b3,
                                               g1, be1, g2, be2,
                                               a_pre, mi, pool, mm);
  scale_kernel<<<16, 256, 0, stream>>>(pool, pw, pb, pg, pbeta, scale, mm, gpar);
  fuse_kernel<<<12593, 256, 0, stream>>>((const float4*)fm, scale,
                                         (const float4*)mi, gpar,
                                         (float4*)out, (float4*)mi4out);
}